// Round 3
// baseline (241.937 us; speedup 1.0000x reference)
//
#include <hip/hip_runtime.h>
#include <hip/hip_bf16.h>
#include <cstdint>

// Problem constants (match reference)
#define B_SZ     256
#define D_DIM    2048
#define N_PROXY  16384
#define P_POS    4
#define K_SEL    54        // BG_KNN + P
#define TEMP_INV 20.0f     // 1/0.05

typedef __bf16 bf16_t;
typedef __bf16 bf16x4 __attribute__((ext_vector_type(4)));
typedef __bf16 bf16x8 __attribute__((ext_vector_type(8)));
typedef float  f32x4  __attribute__((ext_vector_type(4)));

// ---------------------------------------------------------------------------
// Kernel 0: F fp32 [256,2048] -> Fb bf16 in MFMA-A fragment-major layout.
// frag slot g = (mb*64 + kt)*64 + lane holds A[m=mb*16+(lane&15)]
// [k = kt*32 + (lane>>4)*8 + j], j=0..7.  Also zeroes the loss accumulator.
// ---------------------------------------------------------------------------
__global__ __launch_bounds__(256)
void conv_feat(const float* __restrict__ F, bf16_t* __restrict__ Fb,
               float* __restrict__ out) {
    int g    = blockIdx.x * 256 + threadIdx.x;   // 0..65535
    if (g == 0) *out = 0.0f;
    int lane = g & 63;
    int kt   = (g >> 6) & 63;
    int mb   = g >> 12;                          // 0..15
    int frow = lane & 15;
    int quad = (lane >> 4) & 3;
    const float* src = F + (size_t)(mb * 16 + frow) * D_DIM + kt * 32 + quad * 8;
    float4 lo = *(const float4*)src;
    float4 hi = *(const float4*)(src + 4);
    bf16x8 o = { (bf16_t)lo.x, (bf16_t)lo.y, (bf16_t)lo.z, (bf16_t)lo.w,
                 (bf16_t)hi.x, (bf16_t)hi.y, (bf16_t)hi.z, (bf16_t)hi.w };
    *(bf16x8*)(Fb + (size_t)g * 8) = o;
}

// ---------------------------------------------------------------------------
// Kernel 1: Sb = bf16((F @ em.T)/TEMP).  BM=256, BN=64, BK=32, grid 256,
// 512 threads (8 waves, wave w owns rows w*32..w*32+31, all 64 cols).
//
// v4: hand modulo-scheduled K-loop with ZERO register arrays.  Rounds 1-3
// all ran ~2800 cyc/step with every pipe <8% busy — per-step vmcnt drain /
// collapsed prefetch (1 block/CU, so barrier convoys expose full HBM
// latency; compiler-managed arrays defeated the intended schedule).  Now:
//   - E prefetch ring q0..q3 (NAMED float4, depth 4 ~= 3.5 steps in flight)
//   - A double-buffer afA*/afB* (NAMED, depth 1; Fb is L2-resident)
//   - accumulators c00..c13 (NAMED)
//   - 4 macro steps per iteration with hard-coded name/buffer rotation;
//     k appears only in addresses and uniform SCC guards
//   - barrier = s_waitcnt lgkmcnt(0) + s_barrier (NO vmcnt drain: global
//     loads stay in flight across barriers; compiler emits counted vmcnt
//     at the ds_write / MFMA consumption points)
// Data layouts identical to the previously verified kernel.
// ---------------------------------------------------------------------------
__global__ __launch_bounds__(512, 2)
void gemm_score(const bf16_t* __restrict__ Fb, const float* __restrict__ E,
                bf16_t* __restrict__ Sb) {
    const int tid  = threadIdx.x;
    const int bn   = blockIdx.x;          // 64-col n-stripe
    const int lane = tid & 63;
    const int w    = tid >> 6;            // wave 0..7, owns rows w*32..w*32+31
    const int frow = lane & 15;
    const int quad = (lane >> 4) & 3;

    // Double-buffered B tile, MFMA-B fragment-major:
    // frag n (512 bf16 = 1 KB) at n*512, lane-slot l' = fr+16*quad at l'*8.
    __shared__ bf16_t Bls[2][2048];       // 8 KB
    bf16_t* lds0 = &Bls[0][0];
    bf16_t* lds1 = &Bls[1][0];

    // ---- B cooperative staging: 64 rows x 32 fp32 per K-step.
    const int r  = tid >> 3;              // 0..63  (proxy row within stripe)
    const int c4 = (tid & 7) * 4;         // fp32 col within 32
    const float* bsrc = E + (size_t)(bn * 64 + r) * D_DIM + c4;
    const int bdst = (r >> 4) * 512 + ((r & 15) + 16 * (c4 >> 3)) * 8
                   + ((c4 >> 2) & 1) * 4;

    // A frag (m, kt) at Fb[((w*2+m)*64 + kt)*512 + lane*8]
    const bf16_t* Ab0 = Fb + (size_t)((w * 2 + 0) * 64) * 512 + lane * 8;
    const bf16_t* Ab1 = Fb + (size_t)((w * 2 + 1) * 64) * 512 + lane * 8;

    // Named accumulators [m in 0..1][n in 0..3]
    f32x4 c00 = {}, c01 = {}, c02 = {}, c03 = {};
    f32x4 c10 = {}, c11 = {}, c12 = {}, c13 = {};

    // Named E-prefetch ring (slot = data_k & 3) and A double-buffer
    float4 q0, q1, q2, q3;
    bf16x8 afA0, afA1, afB0, afB1;

    // ---- prologue: E data(0..3) -> q0..q3, A(0) -> afA, stage data(0) ----
    q0 = *(const float4*)(bsrc);
    q1 = *(const float4*)(bsrc + 32);
    q2 = *(const float4*)(bsrc + 64);
    q3 = *(const float4*)(bsrc + 96);
    afA0 = *(const bf16x8*)(Ab0);
    afA1 = *(const bf16x8*)(Ab1);
    afB0 = afA0; afB1 = afA1;             // init only; overwritten at step 0
    {
        bf16x4 h = { (bf16_t)q0.x, (bf16_t)q0.y, (bf16_t)q0.z, (bf16_t)q0.w };
        *(bf16x4*)(lds0 + bdst) = h;
    }
    asm volatile("s_waitcnt lgkmcnt(0)" ::: "memory");
    __builtin_amdgcn_s_barrier();
    asm volatile("" ::: "memory");

    // STEP(K): reads buf CUR with A-regs AC*, issues E data(K+4) into QI,
    // loads A(K+1) into AN*, stages E data(K+1) (held in QC) into buf NXT.
    // All register names are macro-bound; K is runtime only in addresses
    // and uniform guards.
#define STEP(K, QI, QC, AC0, AC1, AN0, AN1, LCUR, LNXT)                        \
    {                                                                          \
        bf16x8 bg0 = *(const bf16x8*)(LCUR + 0 * 512 + lane * 8);              \
        bf16x8 bg1 = *(const bf16x8*)(LCUR + 1 * 512 + lane * 8);              \
        bf16x8 bg2 = *(const bf16x8*)(LCUR + 2 * 512 + lane * 8);              \
        bf16x8 bg3 = *(const bf16x8*)(LCUR + 3 * 512 + lane * 8);              \
        if ((K) + 4 < 64)                                                      \
            QI = *(const float4*)(bsrc + ((K) + 4) * 32);                      \
        if ((K) + 1 < 64) {                                                    \
            AN0 = *(const bf16x8*)(Ab0 + ((K) + 1) * 512);                     \
            AN1 = *(const bf16x8*)(Ab1 + ((K) + 1) * 512);                     \
            bf16x4 h = { (bf16_t)QC.x, (bf16_t)QC.y,                           \
                         (bf16_t)QC.z, (bf16_t)QC.w };                         \
            *(bf16x4*)(LNXT + bdst) = h;                                       \
        }                                                                      \
        c00 = __builtin_amdgcn_mfma_f32_16x16x32_bf16(AC0, bg0, c00, 0, 0, 0); \
        c01 = __builtin_amdgcn_mfma_f32_16x16x32_bf16(AC0, bg1, c01, 0, 0, 0); \
        c02 = __builtin_amdgcn_mfma_f32_16x16x32_bf16(AC0, bg2, c02, 0, 0, 0); \
        c03 = __builtin_amdgcn_mfma_f32_16x16x32_bf16(AC0, bg3, c03, 0, 0, 0); \
        c10 = __builtin_amdgcn_mfma_f32_16x16x32_bf16(AC1, bg0, c10, 0, 0, 0); \
        c11 = __builtin_amdgcn_mfma_f32_16x16x32_bf16(AC1, bg1, c11, 0, 0, 0); \
        c12 = __builtin_amdgcn_mfma_f32_16x16x32_bf16(AC1, bg2, c12, 0, 0, 0); \
        c13 = __builtin_amdgcn_mfma_f32_16x16x32_bf16(AC1, bg3, c13, 0, 0, 0); \
        asm volatile("s_waitcnt lgkmcnt(0)" ::: "memory");                     \
        __builtin_amdgcn_s_barrier();                                          \
        asm volatile("" ::: "memory");                                         \
    }

    for (int k0 = 0; k0 < 64; k0 += 4) {
        STEP(k0 + 0, q0, q1, afA0, afA1, afB0, afB1, lds0, lds1)
        STEP(k0 + 1, q1, q2, afB0, afB1, afA0, afA1, lds1, lds0)
        STEP(k0 + 2, q2, q3, afA0, afA1, afB0, afB1, lds0, lds1)
        STEP(k0 + 3, q3, q0, afB0, afB1, afA0, afA1, lds1, lds0)
    }
#undef STEP

    // ---- epilogue: C/D layout col=lane&15, row=quad*4+i; fold 1/TEMP ----
    {
        int gr0 = w * 32 + quad * 4;            // m=0 row base
        int gr1 = gr0 + 16;                     // m=1 row base
#define CWRITE(CV, GR, N)                                                      \
        {                                                                      \
            int gc = bn * 64 + (N) * 16 + frow;                                \
            _Pragma("unroll")                                                  \
            for (int i = 0; i < 4; ++i)                                        \
                Sb[(size_t)((GR) + i) * N_PROXY + gc] =                        \
                    (bf16_t)(CV[i] * TEMP_INV);                                \
        }
        CWRITE(c00, gr0, 0) CWRITE(c01, gr0, 1) CWRITE(c02, gr0, 2) CWRITE(c03, gr0, 3)
        CWRITE(c10, gr1, 0) CWRITE(c11, gr1, 1) CWRITE(c12, gr1, 2) CWRITE(c13, gr1, 3)
#undef CWRITE
    }
}

// ---------------------------------------------------------------------------
// Kernel 2: per-row top-K + log-softmax loss on bf16 scores.
// 512 threads/row, 32 keys/thread; 16-bit radix select with early exit.
// (unchanged this round — one structural change at a time)
// ---------------------------------------------------------------------------
__device__ __forceinline__ float key16_to_float(uint32_t k) {
    uint32_t bits16 = (k & 0x8000u) ? (k ^ 0x8000u) : ((~k) & 0xFFFFu);
    return __uint_as_float(bits16 << 16);
}

__device__ __forceinline__ int block_sum_i(int v, int tid, volatile int* rbuf) {
#pragma unroll
    for (int o = 32; o > 0; o >>= 1) v += __shfl_down(v, o, 64);
    __syncthreads();
    if ((tid & 63) == 0) rbuf[tid >> 6] = v;
    __syncthreads();
    int s = 0;
#pragma unroll
    for (int w = 0; w < 8; ++w) s += rbuf[w];
    return s;
}

__device__ __forceinline__ float block_sum_f(float v, int tid, volatile float* rbuf) {
#pragma unroll
    for (int o = 32; o > 0; o >>= 1) v += __shfl_down(v, o, 64);
    __syncthreads();
    if ((tid & 63) == 0) rbuf[tid >> 6] = v;
    __syncthreads();
    float s = 0.0f;
#pragma unroll
    for (int w = 0; w < 8; ++w) s += rbuf[w];
    return s;
}

__device__ __forceinline__ uint32_t block_max_u(uint32_t v, int tid,
                                                volatile uint32_t* rbuf) {
#pragma unroll
    for (int o = 32; o > 0; o >>= 1) {
        uint32_t w = __shfl_down(v, o, 64);
        v = (w > v) ? w : v;
    }
    __syncthreads();
    if ((tid & 63) == 0) rbuf[tid >> 6] = v;
    __syncthreads();
    uint32_t r = 0;
#pragma unroll
    for (int w = 0; w < 8; ++w) r = rbuf[w] > r ? rbuf[w] : r;
    return r;
}

__global__ __launch_bounds__(512)
void topk_loss(const bf16_t* __restrict__ S, const int* __restrict__ targets,
               const int* __restrict__ plabel, const int* __restrict__ ptable,
               float* __restrict__ out) {
    const int b    = blockIdx.x;
    const int tid  = threadIdx.x;
    const int lane = tid & 63;
    const int wave = tid >> 6;

    __shared__ int      sh_pos[4];
    __shared__ float    sh_pv[4];
    __shared__ int      sh_d;
    __shared__ int      rbuf_i[8];
    __shared__ float    rbuf_f[8];
    __shared__ uint32_t rbuf_u[8];
    __shared__ uint32_t cand_ls[64];
    __shared__ int      candcnt;
    __shared__ float    sh_numbg;

    const bf16_t* row = S + (size_t)b * N_PROXY;

    if (tid == 0) {
        int t  = targets[b];
        int py = plabel[t];
        int pos[4]; int d = 0;
        for (int j = 0; j < 4; ++j) {
            int p = ptable[py * 4 + j];
            bool dup = false;
            for (int i = 0; i < d; ++i) dup = dup || (pos[i] == p);
            if (!dup) pos[d++] = p;
        }
        sh_d = d;
        for (int j = 0; j < 4; ++j) sh_pos[j] = (j < d) ? pos[j] : -1;
        for (int j = 0; j < 4; ++j) sh_pv[j]  = (j < d) ? (float)row[pos[j]] : 0.0f;
        candcnt = 0;
    }
    __syncthreads();

    const int d  = sh_d;
    const int p0 = sh_pos[0], p1 = sh_pos[1], p2 = sh_pos[2], p3 = sh_pos[3];
    float pv[4];
#pragma unroll
    for (int j = 0; j < 4; ++j) pv[j] = sh_pv[j];

    // ---- 32 bf16 logits/thread as 16-bit sortable keys; positives -> 0 ----
    uint32_t keys[32];
#pragma unroll
    for (int j = 0; j < 4; ++j) {
        int g8 = j * 512 + tid;                     // 8-element granule
        ushort v[8];
        *(uint4*)v = *(const uint4*)(row + (size_t)g8 * 8);
#pragma unroll
        for (int q = 0; q < 8; ++q) {
            int idx = g8 * 8 + q;
            bool isp = (idx == p0) | (idx == p1) | (idx == p2) | (idx == p3);
            uint32_t bits = v[q];
            uint32_t key  = (bits & 0x8000u) ? ((~bits) & 0xFFFFu)
                                             : (bits | 0x8000u);
            keys[j * 8 + q] = isp ? 0u : key;
        }
    }

    const int need = K_SEL - d;              // backgrounds in the top-54 set

    // ---- 16-bit radix select with early exit ----
    uint32_t T = 0;
    for (int bit = 15; bit >= 0; --bit) {
        uint32_t cnd = T | (1u << bit);
        int c = 0;
#pragma unroll
        for (int j = 0; j < 32; ++j) c += (keys[j] >= cnd) ? 1 : 0;
        int ct = block_sum_i(c, tid, rbuf_i);
        if (ct >= need) {
            T = cnd;
            if (ct == need) break;           // selected set is exactly top-need
        }
    }
    const float vT = key16_to_float(T);

    // ---- stability max over backgrounds + positives ----
    uint32_t kmax = 0;
#pragma unroll
    for (int j = 0; j < 32; ++j) kmax = keys[j] > kmax ? keys[j] : kmax;
    kmax = block_max_u(kmax, tid, rbuf_u);
    float mx = key16_to_float(kmax);
    for (int j = 0; j < 4; ++j) if (j < d && pv[j] > mx) mx = pv[j];

    // ---- lse over selected set: strict-greater + exact tie fill + pos ----
    int c1 = 0; float se = 0.0f;
#pragma unroll
    for (int j = 0; j < 32; ++j) {
        if (keys[j] > T) { c1 += 1; se += __expf(key16_to_float(keys[j]) - mx); }
    }
    int   c1t = block_sum_i(c1, tid, rbuf_i);
    float set = block_sum_f(se, tid, rbuf_f);
    set += (float)(need - c1t) * __expf(vT - mx);
    for (int j = 0; j < 4; ++j) if (j < d) set += __expf(pv[j] - mx);
    const float lse = mx + logf(set);

    // ---- numerator: distinct positives + top (P-d) background values ----
    float num = 0.0f;
    for (int j = 0; j < 4; ++j) if (j < d) num += pv[j];
    if (d < P_POS) {
#pragma unroll
        for (int j = 0; j < 32; ++j) {
            if (keys[j] > T) {
                int p = atomicAdd(&candcnt, 1);
                cand_ls[p] = keys[j];
            }
        }
        __syncthreads();
        if (wave == 0) {
            const int cc = candcnt;
            uint32_t v = (lane < cc) ? cand_ls[lane] : T;   // pad with T (exact)
            float s = 0.0f;
            const int need2 = P_POS - d;                    // 1..3
            for (int it = 0; it < need2; ++it) {
                uint32_t m = v;
#pragma unroll
                for (int o = 32; o > 0; o >>= 1) {
                    uint32_t w = __shfl_xor(m, o, 64);
                    m = (w > m) ? w : m;
                }
                s += key16_to_float(m);
                unsigned long long msk = __ballot(v == m);
                int first = __ffsll(msk) - 1;
                if (lane == first) v = 0u;
            }
            if (lane == 0) sh_numbg = s;
        }
        __syncthreads();
        num += sh_numbg;
    }

    const float loss_b = lse - num * (1.0f / P_POS);
    if (tid == 0) atomicAdd(out, loss_b * (1.0f / B_SZ));
}

// ---------------------------------------------------------------------------
extern "C" void kernel_launch(void* const* d_in, const int* in_sizes, int n_in,
                              void* d_out, int out_size, void* d_ws, size_t ws_size,
                              hipStream_t stream) {
    const float* F       = (const float*)d_in[0];   // features [256,2048]
    const float* E       = (const float*)d_in[1];   // global_memory [16384,2048]
    const int*   targets = (const int*)d_in[2];     // [256]
    const int*   plabel  = (const int*)d_in[3];     // [32768]
    const int*   ptable  = (const int*)d_in[4];     // [4096,4]

    bf16_t* Fb = (bf16_t*)d_ws;                                     // 1 MB, frag-major
    bf16_t* Sb = (bf16_t*)((char*)d_ws + (size_t)B_SZ * D_DIM * 2); // 8 MB
    float*  out = (float*)d_out;

    // out is zeroed by conv_feat (stream-ordered before topk_loss's atomics)
    hipLaunchKernelGGL(conv_feat, dim3(256), dim3(256), 0, stream, F, Fb, out);
    hipLaunchKernelGGL(gemm_score, dim3(N_PROXY / 64), dim3(512), 0, stream,
                       Fb, E, Sb);
    hipLaunchKernelGGL(topk_loss, dim3(B_SZ), dim3(512), 0, stream,
                       Sb, targets, plabel, ptable, out);
}